// Round 13
// baseline (433.047 us; speedup 1.0000x reference)
//
#include <hip/hip_runtime.h>
#include <hip/hip_fp16.h>

#define NN 20000      // nodes
#define NE 320000     // edges
#define FE 32         // edge feature dim
#define NG 64         // graphs
#define EA_STRIDE 36  // padded LDS row stride (floats)
#define ZTOT4 406024  // float4 count of zeroed region (den+pooled+agg+gacc)

static_assert(NN % 4 == 0, "k_pool assumes full blocks of 4 nodes");
static_assert(NE % 32 == 0, "k_msg assumes whole 16-edge tiles, TPW=2");
static_assert(NE % (10000 * 32) == 0, "k_gatedge coverage");

using f16x8 = __attribute__((ext_vector_type(8))) _Float16;
using f32x4 = __attribute__((ext_vector_type(4))) float;

union AFrag {
    f16x8 v;
    __half2 h2[4];
};

struct Params {
    const float* x; const int* ei; const float* ea; const int* batch;
    const float* We; const float* be; const float* Wroot; const float* bconv;
    const float* Wgat; const float* a_src; const float* a_dst; const float* bgat;
    const float* Wfc1; const float* bfc1; const float* Wfc2; const float* bfc2;
    float* out;
    float* den; float* pooled; float* agg; float* gacc;   // zeroed region, in order
    __half* hpb; float* sc_s; float* sc_d; __half* we2t;
};

static __device__ inline int lbound(const int* b, int key) {
    int lo = 0, hi = NN;
    while (lo < hi) { int mid = (lo + hi) >> 1; if (b[mid] < key) lo = mid + 1; else hi = mid; }
    return lo;
}

// ---------------- K0: init — zero den/pooled/agg/gacc (6.5MB) + build we2t --------
// we2t K permutation: k<512: ks=k>>5, r=k&31, q=r>>3, j=r&7; f=16*(q>>1)+ks;
// i=(q&1)*8+j. k in [512,528): bias row i=k-512; else zero.
__global__ __launch_bounds__(256) void k_init(Params p) {
    int t = blockIdx.x * blockDim.x + threadIdx.x;   // 320 x 256 = 81920 threads
    float4 z4 = {0.f, 0.f, 0.f, 0.f};
    float4* zb = (float4*)p.den;                     // den|pooled|agg|gacc contiguous
    for (int i = t; i < ZTOT4; i += 320 * 256) zb[i] = z4;
    if (t < 16 * 544) {
        int k = t % 544, m = t / 544;
        float v;
        if (k < 512) {
            int ks = k >> 5, r = k & 31, q = r >> 3, j = r & 7;
            int f = 16 * (q >> 1) + ks;
            int i = (q & 1) * 8 + j;
            v = p.We[f * 256 + i * 16 + m];
        } else if (k < 528) v = p.be[(k - 512) * 16 + m];
        else v = 0.f;
        p.we2t[t] = __float2half(v);
    }
}

// ---------------- K1: NNConv msg; round-8 proven TPW=2 LDS pipeline + atomic agg ----
#define TPW 2
__global__ __launch_bounds__(256, 2) void k_msg(Params p) {
    __shared__ float lds[4][2][16 * EA_STRIDE];
    const int lane = threadIdx.x & 63;
    const int wid  = threadIdx.x >> 6;
    const int m    = lane & 15;
    const int quad = lane >> 4;
    const int pp   = quad >> 1;
    const int xh   = (quad & 1) * 8;
    const int eL   = lane >> 3;
    const int fL   = (lane & 7) * 4;

    const int gw = blockIdx.x * 4 + wid;   // 2500 blocks x 4 waves
    const int t0 = gw * TPW;

    const __half* wt = p.we2t + m * 544 + quad * 8;
    f16x8 bfr[17];
    #pragma unroll
    for (int ks = 0; ks < 17; ++ks)
        bfr[ks] = *(const f16x8*)(wt + ks * 32);

    int e0 = t0 * 16;
    int r  = e0 + quad * 4 + (m & 3);
    int s  = p.ei[e0 + m];
    int d  = p.ei[NE + r];
    {
        const float4* s0 = (const float4*)(p.ea + (long)t0 * 512 + lane * 4);
        float4 v0 = s0[0], v1 = s0[64];
        *(float4*)&lds[wid][0][eL * EA_STRIDE + fL]       = v0;
        *(float4*)&lds[wid][0][(8 + eL) * EA_STRIDE + fL] = v1;
    }
    float xf[8];
    {
        const float4* xr = (const float4*)(p.x + s * 16 + xh);
        float4 a0 = xr[0], a1 = xr[1];
        xf[0]=a0.x; xf[1]=a0.y; xf[2]=a0.z; xf[3]=a0.w;
        xf[4]=a1.x; xf[5]=a1.y; xf[6]=a1.z; xf[7]=a1.w;
    }

    int buf = 0;
    #pragma unroll
    for (int it = 0; it < TPW; ++it) {
        const int tile = t0 + it;
        const bool hasnext = it < TPW - 1;

        float4 nv0, nv1;
        int s_n = 0, d_n = 0;
        if (hasnext) {
            const float4* sn = (const float4*)(p.ea + (long)(tile + 1) * 512 + lane * 4);
            nv0 = sn[0]; nv1 = sn[64];
            int e0n = (tile + 1) * 16;
            int rn  = e0n + quad * 4 + (m & 3);
            s_n = p.ei[e0n + m];
            d_n = p.ei[NE + rn];
        }

        float4 ev[4];
        #pragma unroll
        for (int q = 0; q < 4; ++q)
            ev[q] = *(const float4*)&lds[wid][buf][m * EA_STRIDE + pp * 16 + q * 4];

        __half2 xp[4];
        #pragma unroll
        for (int j = 0; j < 4; ++j)
            xp[j] = __float22half2_rn(make_float2(xf[2*j], xf[2*j+1]));

        f32x4 acc = {0.f, 0.f, 0.f, 0.f};
        #pragma unroll
        for (int ks = 0; ks < 16; ++ks) {
            float evv = ((const float*)ev)[ks];
            __half2 eh = __float2half2_rn(evv);
            AFrag a;
            #pragma unroll
            for (int j = 0; j < 4; ++j) a.h2[j] = __hmul2(eh, xp[j]);
            acc = __builtin_amdgcn_mfma_f32_16x16x32_f16(a.v, bfr[ks], acc, 0, 0, 0);
        }
        {
            AFrag a;
            #pragma unroll
            for (int j = 0; j < 4; ++j) a.h2[j] = xp[j];
            acc = __builtin_amdgcn_mfma_f32_16x16x32_f16(a.v, bfr[16], acc, 0, 0, 0);
        }

        if (hasnext) {
            const float4* xr = (const float4*)(p.x + s_n * 16 + xh);
            float4 a0 = xr[0], a1 = xr[1];
            xf[0]=a0.x; xf[1]=a0.y; xf[2]=a0.z; xf[3]=a0.w;
            xf[4]=a1.x; xf[5]=a1.y; xf[6]=a1.z; xf[7]=a1.w;
        }

        // C row = quad*4+rr (edge), col = m (feature); lane (quad<<4)|rr holds dst
        #pragma unroll
        for (int rr = 0; rr < 4; ++rr) {
            int dd = __shfl(d, (quad << 4) | rr);
            atomicAdd(&p.agg[dd * 16 + m], acc[rr]);
        }

        if (hasnext) {
            buf ^= 1;
            *(float4*)&lds[wid][buf][eL * EA_STRIDE + fL]       = nv0;
            *(float4*)&lds[wid][buf][(8 + eL) * EA_STRIDE + fL] = nv1;
            s = s_n; d = d_n;
        }
    }
}

// ---------------- K2: node — h, hp, scores (direct agg read) ----------------
__global__ __launch_bounds__(256) void k_node(Params p) {
    int n = (blockIdx.x * blockDim.x + threadIdx.x) >> 6;
    int lane = threadIdx.x & 63;
    if (n >= NN) return;
    int o = lane & 15;
    float agv = p.agg[n * 16 + o];
    float xv = p.x[n * 16 + o];
    float acc = p.bconv[o] + agv;
    #pragma unroll
    for (int i = 0; i < 16; ++i) acc += __shfl(xv, i) * p.Wroot[i * 16 + o];
    float hv = fmaxf(acc, 0.f);
    float hpacc = 0.f;
    #pragma unroll
    for (int i = 0; i < 16; ++i) hpacc += __shfl(hv, i) * p.Wgat[i * 64 + lane];
    p.hpb[(long)n * 64 + lane] = __float2half(hpacc);
    float ss = hpacc * p.a_src[lane];
    float sd = hpacc * p.a_dst[lane];
    #pragma unroll
    for (int off = 32; off; off >>= 1) {
        ss += __shfl_xor(ss, off);
        sd += __shfl_xor(sd, off);
    }
    if (lane == 0) { p.sc_s[n] = ss; p.sc_d[n] = sd; }
}

// ---------------- K3: GAT aggregation — EDGE-PARALLEL streaming ----------------
// Replaces the node-centric gather kernel (~100-110us, latency-dead at 12-29% occ:
// per-node serial chains of ~16 dependent remote-row gathers). Here: coalesced ei
// stream (no esrc/prep at all), hp[s] row gathers are independent across 320k
// edges (throughput-parallel, no shfl chains), segment-sum via fire-and-forget
// f32 atomics into den (NN) and gacc (NN x 64, 5MB L2-distributed).
// Wave layout: 4 edges x 16 feature-groups (4 feats each). 8 iters -> 32 edges/wave;
// grid 2500 x 4 waves x 32 = 320000.
#define GE_ITERS 8
__global__ __launch_bounds__(256) void k_gatedge(Params p) {
    const int lane = threadIdx.x & 63;
    const int wv   = threadIdx.x >> 6;
    const int gw   = blockIdx.x * 4 + wv;       // [0,10000)
    const int esub = lane >> 4;                 // edge within group [0,4)
    const int f4   = (lane & 15) * 4;           // feature base

    #pragma unroll
    for (int i = 0; i < GE_ITERS; ++i) {
        int e = gw * (4 * GE_ITERS) + i * 4 + esub;
        int s = p.ei[e];
        int d = p.ei[NE + e];
        float sc = p.sc_s[s] + p.sc_d[d];
        sc = (sc >= 0.f) ? sc : 0.2f * sc;
        float w = __expf(sc);
        union { float2 f2; __half2 h2[2]; } u;
        u.f2 = *(const float2*)(p.hpb + (long)s * 64 + f4);
        float2 h0 = __half22float2(u.h2[0]);
        float2 h1 = __half22float2(u.h2[1]);
        if ((lane & 15) == 0) atomicAdd(&p.den[d], w);
        float* gb = p.gacc + (long)d * 64 + f4;
        atomicAdd(gb + 0, w * h0.x);
        atomicAdd(gb + 1, w * h0.y);
        atomicAdd(gb + 2, w * h1.x);
        atomicAdd(gb + 3, w * h1.y);
    }
}

// ---------------- K4: pool — self-loop + normalize + relu + block-reduced pool ------
// Fully coalesced node-parallel pass: wave per node, lane = feature.
__global__ __launch_bounds__(256) void k_pool(Params p) {
    __shared__ float red[4][64];
    __shared__ int sgid[4];
    int wv = threadIdx.x >> 6;
    int n = (blockIdx.x * blockDim.x + threadIdx.x) >> 6;   // grid exact: NN/4
    int lane = threadIdx.x & 63;
    int gid = p.batch[n];
    float es = p.sc_s[n] + p.sc_d[n];
    es = (es >= 0.f) ? es : 0.2f * es;
    float e_self = __expf(es);
    float hp = __half2float(p.hpb[(long)n * 64 + lane]);
    float num = p.gacc[(long)n * 64 + lane] + e_self * hp;
    float den = p.den[n] + e_self;
    float g = fmaxf(num / den + p.bgat[lane], 0.f);

    // batch sorted -> block's 4 waves usually share gid: one atomic set per block
    red[wv][lane] = g;
    if (lane == 0) sgid[wv] = gid;
    __syncthreads();
    bool leader = true;
    #pragma unroll
    for (int w2 = 0; w2 < 3; ++w2)
        if (w2 < wv && sgid[w2] == gid) leader = false;
    if (leader) {
        float tot = g;
        #pragma unroll
        for (int w2 = 1; w2 < 4; ++w2)
            if (w2 > wv && sgid[w2] == gid) tot += red[w2][lane];
        atomicAdd(&p.pooled[gid * 64 + lane], tot);
    }
}

// ---------------- K5: MLP head; one block (128 thr) per graph ----------------
__global__ __launch_bounds__(128) void k_head(Params p) {
    int g = blockIdx.x;
    int t = threadIdx.x;
    __shared__ float pl[64];
    __shared__ float zl[128];
    int r0 = lbound(p.batch, g);
    int r1 = lbound(p.batch, g + 1);
    float inv = 1.f / (float)((r1 - r0) > 0 ? (r1 - r0) : 1);
    if (t < 64) pl[t] = p.pooled[g * 64 + t] * inv;
    __syncthreads();
    float a = p.bfc1[t];
    #pragma unroll 8
    for (int i = 0; i < 64; ++i) a += pl[i] * p.Wfc1[i * 128 + t];
    zl[t] = fmaxf(a, 0.f);
    __syncthreads();
    if (t < 64) {
        float v = zl[t] * p.Wfc2[t] + zl[t + 64] * p.Wfc2[t + 64];
        #pragma unroll
        for (int off = 32; off; off >>= 1) v += __shfl_xor(v, off);
        if (t == 0) p.out[g] = v + p.bfc2[0];
    }
}

extern "C" void kernel_launch(void* const* d_in, const int* in_sizes, int n_in,
                              void* d_out, int out_size, void* d_ws, size_t ws_size,
                              hipStream_t stream) {
    (void)in_sizes; (void)n_in; (void)out_size; (void)ws_size;
    char* w = (char*)d_ws;
    // zeroed region (contiguous, float4-zeroed by k_init): den|pooled|agg|gacc
    size_t o_dn = 0;                                // den     NN f32      (80000 B)
    size_t o_pl = o_dn + (size_t)NN * 4;            // pooled  NG*64 f32   (16384 B)
    size_t o_ag = o_pl + (size_t)NG * 64 * 4;       // agg     NN*16 f32   (1280000 B)
    size_t o_gc = o_ag + (size_t)NN * 16 * 4;       // gacc    NN*64 f32   (5120000 B)
    size_t o_ze = o_gc + (size_t)NN * 64 * 4;       // end of zeroed = 6496384 = ZTOT4*16
    size_t o_hp = (o_ze + 15) & ~(size_t)15;        // hpb     NN*64 f16
    size_t o_ss = o_hp + (size_t)NN * 64 * 2;       // sc_s    NN f32
    size_t o_sd = o_ss + (size_t)NN * 4;            // sc_d    NN f32
    size_t o_wt = o_sd + (size_t)NN * 4;            // we2t    16*544 f16
    o_wt = (o_wt + 15) & ~(size_t)15;

    Params P;
    P.x     = (const float*)d_in[0];
    P.ei    = (const int*)d_in[1];
    P.ea    = (const float*)d_in[2];
    P.batch = (const int*)d_in[3];
    P.We    = (const float*)d_in[4];
    P.be    = (const float*)d_in[5];
    P.Wroot = (const float*)d_in[6];
    P.bconv = (const float*)d_in[7];
    P.Wgat  = (const float*)d_in[8];
    P.a_src = (const float*)d_in[9];
    P.a_dst = (const float*)d_in[10];
    P.bgat  = (const float*)d_in[11];
    P.Wfc1  = (const float*)d_in[12];
    P.bfc1  = (const float*)d_in[13];
    P.Wfc2  = (const float*)d_in[14];
    P.bfc2  = (const float*)d_in[15];
    P.out   = (float*)d_out;
    P.den    = (float*)(w + o_dn);
    P.pooled = (float*)(w + o_pl);
    P.agg    = (float*)(w + o_ag);
    P.gacc   = (float*)(w + o_gc);
    P.hpb    = (__half*)(w + o_hp);
    P.sc_s   = (float*)(w + o_ss);
    P.sc_d   = (float*)(w + o_sd);
    P.we2t   = (__half*)(w + o_wt);

    k_init<<<320, 256, 0, stream>>>(P);            // zero 6.5MB + we2t
    k_msg<<<2500, 256, 0, stream>>>(P);            // NNConv edge MFMA -> agg
    k_node<<<(NN + 3) / 4, 256, 0, stream>>>(P);   // h, hp, scores
    k_gatedge<<<2500, 256, 0, stream>>>(P);        // GAT segment-sums, edge-parallel
    k_pool<<<NN / 4, 256, 0, stream>>>(P);         // normalize + relu + mean-pool
    k_head<<<NG, 128, 0, stream>>>(P);             // MLP head
}

// Round 14
// 178.964 us; speedup vs baseline: 2.4197x; 2.4197x over previous
//
#include <hip/hip_runtime.h>
#include <hip/hip_fp16.h>

#define NN 20000      // nodes
#define NE 320000     // edges
#define FE 32         // edge feature dim
#define NG 64         // graphs
#define EA_STRIDE 36  // padded LDS row stride (floats)
#define MAXDEG 64     // fixed-stride in-edge slots; P(Poisson(16) > 64) ~ 1e-22

static_assert(NN % 4 == 0, "k_gat assumes full blocks of 4 nodes");
static_assert(NE % 32 == 0, "k_msg assumes whole 16-edge tiles, TPW=2");

using f16x8 = __attribute__((ext_vector_type(8))) _Float16;
using f32x4 = __attribute__((ext_vector_type(4))) float;

union AFrag {
    f16x8 v;
    __half2 h2[4];
};

struct Params {
    const float* x; const int* ei; const float* ea; const int* batch;
    const float* We; const float* be; const float* Wroot; const float* bconv;
    const float* Wgat; const float* a_src; const float* a_dst; const float* bgat;
    const float* Wfc1; const float* bfc1; const float* Wfc2; const float* bfc2;
    float* out;
    int* deg; float* agg; float* pooled; int* esrc;
    __half* hpb; float* sc_s; float* sc_d; __half* we2t;
};

static __device__ inline int lbound(const int* b, int key) {
    int lo = 0, hi = NN;
    while (lo < hi) { int mid = (lo + hi) >> 1; if (b[mid] < key) lo = mid + 1; else hi = mid; }
    return lo;
}

// ---------------- K0: prep — fixed-stride in-edge lists + we2t build ----------------
// slot r = atomicAdd(deg[d]) directly indexes esrc[d*64+r]. No prefix scan.
// we2t K permutation: k in [0,512): ks=k>>5, r=k&31, q=r>>3, j=r&7;
// f=16*(q>>1)+ks; i=(q&1)*8+j. k in [512,528): bias row i=k-512; else zero.
__global__ __launch_bounds__(256) void k_prep(Params p) {
    int e = blockIdx.x * blockDim.x + threadIdx.x;
    if (e < NE) {
        int d = p.ei[NE + e];
        int r = atomicAdd(&p.deg[d], 1);
        if (r < MAXDEG) p.esrc[(d << 6) + r] = p.ei[e];
    }
    if (e < 16 * 544) {
        int k = e % 544, m = e / 544;
        float v;
        if (k < 512) {
            int ks = k >> 5, r = k & 31, q = r >> 3, j = r & 7;
            int f = 16 * (q >> 1) + ks;
            int i = (q & 1) * 8 + j;
            v = p.We[f * 256 + i * 16 + m];
        } else if (k < 528) v = p.be[(k - 512) * 16 + m];
        else v = 0.f;
        p.we2t[e] = __float2half(v);
    }
}

// ---------------- K1: NNConv msg; TPW=2 LDS pipeline + atomic agg ----------------
#define TPW 2
__global__ __launch_bounds__(256, 2) void k_msg(Params p) {
    __shared__ float lds[4][2][16 * EA_STRIDE];
    const int lane = threadIdx.x & 63;
    const int wid  = threadIdx.x >> 6;
    const int m    = lane & 15;
    const int quad = lane >> 4;
    const int pp   = quad >> 1;
    const int xh   = (quad & 1) * 8;
    const int eL   = lane >> 3;
    const int fL   = (lane & 7) * 4;

    const int gw = blockIdx.x * 4 + wid;   // 2500 blocks x 4 waves
    const int t0 = gw * TPW;

    // B fragments once per wave (we2t 17.4KB, L2-resident)
    const __half* wt = p.we2t + m * 544 + quad * 8;
    f16x8 bfr[17];
    #pragma unroll
    for (int ks = 0; ks < 17; ++ks)
        bfr[ks] = *(const f16x8*)(wt + ks * 32);

    // ---- prologue: tile0 scalars + ea + x ----
    int e0 = t0 * 16;
    int r  = e0 + quad * 4 + (m & 3);
    int s  = p.ei[e0 + m];
    int d  = p.ei[NE + r];
    {
        const float4* s0 = (const float4*)(p.ea + (long)t0 * 512 + lane * 4);
        float4 v0 = s0[0], v1 = s0[64];
        *(float4*)&lds[wid][0][eL * EA_STRIDE + fL]       = v0;
        *(float4*)&lds[wid][0][(8 + eL) * EA_STRIDE + fL] = v1;
    }
    float xf[8];
    {
        const float4* xr = (const float4*)(p.x + s * 16 + xh);
        float4 a0 = xr[0], a1 = xr[1];
        xf[0]=a0.x; xf[1]=a0.y; xf[2]=a0.z; xf[3]=a0.w;
        xf[4]=a1.x; xf[5]=a1.y; xf[6]=a1.z; xf[7]=a1.w;
    }

    int buf = 0;
    #pragma unroll
    for (int it = 0; it < TPW; ++it) {
        const int tile = t0 + it;
        const bool hasnext = it < TPW - 1;

        // prefetch next tile's independent loads (ea + scalars) — issue early
        float4 nv0, nv1;
        int s_n = 0, d_n = 0;
        if (hasnext) {
            const float4* sn = (const float4*)(p.ea + (long)(tile + 1) * 512 + lane * 4);
            nv0 = sn[0]; nv1 = sn[64];
            int e0n = (tile + 1) * 16;
            int rn  = e0n + quad * 4 + (m & 3);
            s_n = p.ei[e0n + m];
            d_n = p.ei[NE + rn];
        }

        // this tile's ea from LDS
        float4 ev[4];
        #pragma unroll
        for (int q = 0; q < 4; ++q)
            ev[q] = *(const float4*)&lds[wid][buf][m * EA_STRIDE + pp * 16 + q * 4];

        __half2 xp[4];
        #pragma unroll
        for (int j = 0; j < 4; ++j)
            xp[j] = __float22half2_rn(make_float2(xf[2*j], xf[2*j+1]));

        f32x4 acc = {0.f, 0.f, 0.f, 0.f};
        #pragma unroll
        for (int ks = 0; ks < 16; ++ks) {
            float evv = ((const float*)ev)[ks];
            __half2 eh = __float2half2_rn(evv);
            AFrag a;
            #pragma unroll
            for (int j = 0; j < 4; ++j) a.h2[j] = __hmul2(eh, xp[j]);
            acc = __builtin_amdgcn_mfma_f32_16x16x32_f16(a.v, bfr[ks], acc, 0, 0, 0);
        }
        {
            AFrag a;
            #pragma unroll
            for (int j = 0; j < 4; ++j) a.h2[j] = xp[j];
            acc = __builtin_amdgcn_mfma_f32_16x16x32_f16(a.v, bfr[16], acc, 0, 0, 0);
        }

        // dependent x gather for next tile — after compute, before atomics
        if (hasnext) {
            const float4* xr = (const float4*)(p.x + s_n * 16 + xh);
            float4 a0 = xr[0], a1 = xr[1];
            xf[0]=a0.x; xf[1]=a0.y; xf[2]=a0.z; xf[3]=a0.w;
            xf[4]=a1.x; xf[5]=a1.y; xf[6]=a1.z; xf[7]=a1.w;
        }

        // MFMA C layout: row = quad*4+rr (edge in tile), col = m (feature).
        // Lane (quad<<4)|rr holds that edge's dst. Fire-and-forget atomics.
        #pragma unroll
        for (int rr = 0; rr < 4; ++rr) {
            int dd = __shfl(d, (quad << 4) | rr);
            atomicAdd(&p.agg[dd * 16 + m], acc[rr]);
        }

        if (hasnext) {
            buf ^= 1;
            *(float4*)&lds[wid][buf][eL * EA_STRIDE + fL]       = nv0;
            *(float4*)&lds[wid][buf][(8 + eL) * EA_STRIDE + fL] = nv1;
            s = s_n; d = d_n;
        }
    }
}

// ---------------- K2: node — h, hp, scores (direct agg read) ----------------
__global__ __launch_bounds__(256) void k_node(Params p) {
    int n = (blockIdx.x * blockDim.x + threadIdx.x) >> 6;
    int lane = threadIdx.x & 63;
    if (n >= NN) return;
    int o = lane & 15;
    float agv = p.agg[n * 16 + o];
    float xv = p.x[n * 16 + o];
    float acc = p.bconv[o] + agv;
    #pragma unroll
    for (int i = 0; i < 16; ++i) acc += __shfl(xv, i) * p.Wroot[i * 16 + o];
    float hv = fmaxf(acc, 0.f);
    float hpacc = 0.f;
    #pragma unroll
    for (int i = 0; i < 16; ++i) hpacc += __shfl(hv, i) * p.Wgat[i * 64 + lane];
    p.hpb[(long)n * 64 + lane] = __float2half(hpacc);
    float ss = hpacc * p.a_src[lane];
    float sd = hpacc * p.a_dst[lane];
    #pragma unroll
    for (int off = 32; off; off >>= 1) {
        ss += __shfl_xor(ss, off);
        sd += __shfl_xor(sd, off);
    }
    if (lane == 0) { p.sc_s[n] = ss; p.sc_d[n] = sd; }
}

// ---------------- K3: GAT + block-reduced mean-pool accumulation ----------------
// ONE change vs round-8 (178.5us): __launch_bounds__(256, 2). Round-12's profile
// showed this body compiles to 28 VGPRs under the default 8-wave target — not
// enough to keep the intended 8 hpb loads in flight (8 dest + 16 addr regs), so
// the compiler serializes them. 128-VGPR budget lets the 8-deep batch actually
// issue; occupancy stays >=2 waves/SIMD (grid has 20000 waves).
__global__ __launch_bounds__(256, 2) void k_gat(Params p) {
    __shared__ float red[4][64];
    __shared__ int sgid[4];
    int wv = threadIdx.x >> 6;
    int d = (blockIdx.x * blockDim.x + threadIdx.x) >> 6;   // grid exact: NN/4 blocks
    int lane = threadIdx.x & 63;
    float sdv = p.sc_d[d];
    int gid = p.batch[d];
    float es = p.sc_s[d] + sdv;
    es = (es >= 0.f) ? es : 0.2f * es;
    float l0 = __expf(es);
    float acc = l0 * __half2float(p.hpb[(long)d * 64 + lane]);

    int cnt = p.deg[d]; if (cnt > MAXDEG) cnt = MAXDEG;     // wave-uniform
    bool valid = lane < cnt;
    int s = valid ? p.esrc[(d << 6) + lane] : 0;
    float sc = valid ? p.sc_s[s] + sdv : 0.f;
    sc = (sc >= 0.f) ? sc : 0.2f * sc;
    float pj = valid ? __expf(sc) : 0.f;
    float lsum = pj;

    int k2 = 0;
    for (; k2 + 8 <= cnt; k2 += 8) {       // 8 hpb loads in flight
        int   e0 = __shfl(s, k2),     e1 = __shfl(s, k2 + 1);
        int   e2 = __shfl(s, k2 + 2), e3 = __shfl(s, k2 + 3);
        int   e4 = __shfl(s, k2 + 4), e5 = __shfl(s, k2 + 5);
        int   e6 = __shfl(s, k2 + 6), e7 = __shfl(s, k2 + 7);
        float q0 = __shfl(pj, k2),     q1 = __shfl(pj, k2 + 1);
        float q2 = __shfl(pj, k2 + 2), q3 = __shfl(pj, k2 + 3);
        float q4 = __shfl(pj, k2 + 4), q5 = __shfl(pj, k2 + 5);
        float q6 = __shfl(pj, k2 + 6), q7 = __shfl(pj, k2 + 7);
        float h0 = __half2float(p.hpb[(long)e0 * 64 + lane]);
        float h1 = __half2float(p.hpb[(long)e1 * 64 + lane]);
        float h2 = __half2float(p.hpb[(long)e2 * 64 + lane]);
        float h3 = __half2float(p.hpb[(long)e3 * 64 + lane]);
        float h4 = __half2float(p.hpb[(long)e4 * 64 + lane]);
        float h5 = __half2float(p.hpb[(long)e5 * 64 + lane]);
        float h6 = __half2float(p.hpb[(long)e6 * 64 + lane]);
        float h7 = __half2float(p.hpb[(long)e7 * 64 + lane]);
        acc += q0 * h0 + q1 * h1 + q2 * h2 + q3 * h3
             + q4 * h4 + q5 * h5 + q6 * h6 + q7 * h7;
    }
    for (; k2 + 4 <= cnt; k2 += 4) {
        int   e0 = __shfl(s, k2),     e1 = __shfl(s, k2 + 1);
        int   e2 = __shfl(s, k2 + 2), e3 = __shfl(s, k2 + 3);
        float q0 = __shfl(pj, k2),     q1 = __shfl(pj, k2 + 1);
        float q2 = __shfl(pj, k2 + 2), q3 = __shfl(pj, k2 + 3);
        float h0 = __half2float(p.hpb[(long)e0 * 64 + lane]);
        float h1 = __half2float(p.hpb[(long)e1 * 64 + lane]);
        float h2 = __half2float(p.hpb[(long)e2 * 64 + lane]);
        float h3 = __half2float(p.hpb[(long)e3 * 64 + lane]);
        acc += q0 * h0 + q1 * h1 + q2 * h2 + q3 * h3;
    }
    for (; k2 < cnt; ++k2) {
        int sk = __shfl(s, k2);
        float pk = __shfl(pj, k2);
        acc += pk * __half2float(p.hpb[(long)sk * 64 + lane]);
    }

    #pragma unroll
    for (int off = 32; off; off >>= 1) lsum += __shfl_xor(lsum, off);
    float g = acc / (lsum + l0) + p.bgat[lane];
    g = fmaxf(g, 0.f);

    // batch sorted → the 4 waves of a block almost always share gid: reduce in LDS,
    // one atomic per (block, gid) instead of per wave.
    red[wv][lane] = g;
    if (lane == 0) sgid[wv] = gid;
    __syncthreads();
    bool leader = true;
    #pragma unroll
    for (int w2 = 0; w2 < 3; ++w2)
        if (w2 < wv && sgid[w2] == gid) leader = false;
    if (leader) {
        float tot = g;
        #pragma unroll
        for (int w2 = 1; w2 < 4; ++w2)
            if (w2 > wv && sgid[w2] == gid) tot += red[w2][lane];
        atomicAdd(&p.pooled[gid * 64 + lane], tot);
    }
}

// ---------------- K4: MLP head; one block (128 thr) per graph ----------------
__global__ __launch_bounds__(128) void k_head(Params p) {
    int g = blockIdx.x;
    int t = threadIdx.x;
    __shared__ float pl[64];
    __shared__ float zl[128];
    int r0 = lbound(p.batch, g);
    int r1 = lbound(p.batch, g + 1);
    float inv = 1.f / (float)((r1 - r0) > 0 ? (r1 - r0) : 1);
    if (t < 64) pl[t] = p.pooled[g * 64 + t] * inv;
    __syncthreads();
    float a = p.bfc1[t];
    #pragma unroll 8
    for (int i = 0; i < 64; ++i) a += pl[i] * p.Wfc1[i * 128 + t];
    zl[t] = fmaxf(a, 0.f);
    __syncthreads();
    if (t < 64) {
        float v = zl[t] * p.Wfc2[t] + zl[t + 64] * p.Wfc2[t + 64];
        #pragma unroll
        for (int off = 32; off; off >>= 1) v += __shfl_xor(v, off);
        if (t == 0) p.out[g] = v + p.bfc2[0];
    }
}

extern "C" void kernel_launch(void* const* d_in, const int* in_sizes, int n_in,
                              void* d_out, int out_size, void* d_ws, size_t ws_size,
                              hipStream_t stream) {
    (void)in_sizes; (void)n_in; (void)out_size; (void)ws_size;
    char* w = (char*)d_ws;
    size_t o0  = 0;                             // deg      NN int         (zeroed)
    size_t o1  = o0 + (size_t)NN * 4;           // agg      NN*16 f32      (zeroed)
    size_t o2  = o1 + (size_t)NN * 16 * 4;      // pooled   NG*64 f32      (zeroed)
    size_t oz  = o2 + (size_t)NG * 64 * 4;      // end of zeroed region (~1.4MB)
    size_t o3  = (oz + 63) & ~(size_t)63;       // esrc     NN*64 int (5.12MB, write-once)
    size_t o4  = o3 + (size_t)NN * 64 * 4;      // hpb      NN*64 f16
    size_t o5  = o4 + (size_t)NN * 64 * 2;      // sc_s     NN f32
    size_t o6  = o5 + (size_t)NN * 4;           // sc_d     NN f32
    size_t o7  = o6 + (size_t)NN * 4;           // we2t     16*544 f16
    o7 = (o7 + 15) & ~(size_t)15;

    Params P;
    P.x     = (const float*)d_in[0];
    P.ei    = (const int*)d_in[1];
    P.ea    = (const float*)d_in[2];
    P.batch = (const int*)d_in[3];
    P.We    = (const float*)d_in[4];
    P.be    = (const float*)d_in[5];
    P.Wroot = (const float*)d_in[6];
    P.bconv = (const float*)d_in[7];
    P.Wgat  = (const float*)d_in[8];
    P.a_src = (const float*)d_in[9];
    P.a_dst = (const float*)d_in[10];
    P.bgat  = (const float*)d_in[11];
    P.Wfc1  = (const float*)d_in[12];
    P.bfc1  = (const float*)d_in[13];
    P.Wfc2  = (const float*)d_in[14];
    P.bfc2  = (const float*)d_in[15];
    P.out   = (float*)d_out;
    P.deg    = (int*)(w + o0);
    P.agg    = (float*)(w + o1);
    P.pooled = (float*)(w + o2);
    P.esrc   = (int*)(w + o3);
    P.hpb    = (__half*)(w + o4);
    P.sc_s   = (float*)(w + o5);
    P.sc_d   = (float*)(w + o6);
    P.we2t   = (__half*)(w + o7);

    (void)hipMemsetAsync(w, 0, oz, stream);   // deg + agg + pooled (~1.4MB)
    k_prep<<<(NE + 255) / 256, 256, 0, stream>>>(P);
    k_msg<<<2500, 256, 0, stream>>>(P);
    k_node<<<(NN + 3) / 4, 256, 0, stream>>>(P);
    k_gat<<<NN / 4, 256, 0, stream>>>(P);
    k_head<<<NG, 128, 0, stream>>>(P);
}